// Round 15
// baseline (85.555 us; speedup 1.0000x reference)
//
#include <hip/hip_runtime.h>
#include <hip/hip_bf16.h>

#define NPIX 4096   // 64*64 pixels per batch
#define CCH  64     // channels
#define NB   8      // batch
#define KVBLK 64    // j-tile per pipeline stage (32KB LDS dbuf)

typedef __attribute__((ext_vector_type(8)))  short short8;   // 8 bf16 MFMA A/B frag (32x32x16)
typedef __attribute__((ext_vector_type(4)))  float f32x4;
typedef __attribute__((ext_vector_type(16))) float f32x16;   // 32x32 MFMA C/D frag

#define LOG2E   1.44269504f

// ---------------------------------------------------------------------------
// Kernel 1: fused 1x1-conv projections, m-split across blocks (R14-proven).
//   m=0: Q[b][i][oc] = log2e * (W1 x + b1)   (bf16 pixel-major)
//   m=1: G[b][j][oc] =         (W2 x + b2)   (bf16 pixel-major)
//   m=2: K[b][oc][j] =         (W3 x + b3)   (bf16 channel-major)
// ---------------------------------------------------------------------------
__global__ __launch_bounds__(256) void proj_kernel(
    const float* __restrict__ x,
    const float* __restrict__ W1, const float* __restrict__ b1,
    const float* __restrict__ W2, const float* __restrict__ b2,
    const float* __restrict__ W3, const float* __restrict__ b3,
    __hip_bfloat16* __restrict__ Q, __hip_bfloat16* __restrict__ G,
    __hip_bfloat16* __restrict__ K)
{
    const int m    = blockIdx.x % 3;
    const int tile = blockIdx.x / 3;
    const int b    = tile >> 6;
    const int i0   = (tile & 63) << 6;

    const float* W  = (m == 0) ? W1 : (m == 1) ? W2 : W3;
    const float* bv = (m == 0) ? b1 : (m == 1) ? b2 : b3;

    __shared__ float xs[64][65];      // xs[c][p]
    __shared__ float Wt[64][68];      // Wt[c][oc], rows 16B-aligned

    for (int e = threadIdx.x; e < 4096; e += 256) {
        const int c = e >> 6, p = e & 63;
        xs[c][p] = x[(size_t)b * CCH * NPIX + (size_t)c * NPIX + i0 + p];
        Wt[e & 63][e >> 6] = W[e];
    }
    __syncthreads();

    const int p = threadIdx.x & 63;
    const int g = threadIdx.x >> 6;

    float acc[16];
    #pragma unroll
    for (int oo = 0; oo < 16; ++oo) acc[oo] = bv[g * 16 + oo];

    for (int c = 0; c < 64; ++c) {
        const float xv = xs[c][p];
        const f32x4* w = (const f32x4*)&Wt[c][g * 16];
        #pragma unroll
        for (int qq = 0; qq < 4; ++qq) {
            const f32x4 a = w[qq];
            #pragma unroll
            for (int j = 0; j < 4; ++j)
                acc[qq * 4 + j] += a[j] * xv;
        }
    }

    const int i = i0 + p;
    if (m == 0) {
        #pragma unroll
        for (int oo = 0; oo < 16; ++oo)
            Q[(size_t)b * NPIX * CCH + (size_t)i * CCH + g * 16 + oo] =
                __float2bfloat16(acc[oo] * LOG2E);
    } else if (m == 1) {
        #pragma unroll
        for (int oo = 0; oo < 16; ++oo)
            G[(size_t)b * NPIX * CCH + (size_t)i * CCH + g * 16 + oo] =
                __float2bfloat16(acc[oo]);
    } else {
        #pragma unroll
        for (int oo = 0; oo < 16; ++oo)
            K[(size_t)b * CCH * NPIX + (size_t)(g * 16 + oo) * NPIX + i] =
                __float2bfloat16(acc[oo]);
    }
}

// ---------------------------------------------------------------------------
// Kernel 2: LDS-staged flash attention, 32x32x16 MFMA, swapped QK^T, KVBLK=64.
// 8 waves x 32 rows (512 threads). R15 delta: two-jb software pipeline —
// both jb's G-frags loaded and both QK MFMA chains issued back-to-back
// (independent dep chains -> scheduler interleaves; chain-1 latency hides
// under chain-0's exp/pack). Per-element math bit-identical to R14.
// Compiler-visible exp->pack chain (builtin exp2f + __float22bfloat162_rn);
// only permlane stays asm (R3-R14-proven safe boundary).
// 32x32x16 bf16 layouts (m74/m101-verified C/D; A/B contiguous-8k):
//   A: row=lane&31, k=8*(lane>>5)+t     B: col=lane&31, k=8*(lane>>5)+t
//   C/D: col=lane&31, row=(r&3)+8*(r>>2)+4*(lane>>5)
// LDS per buf: G[64 rows][128B] swz ^(row&7)<<4, K[64 c-rows][128B] same.
// ---------------------------------------------------------------------------
__device__ __forceinline__ void gload_lds16(const void* g, void* l) {
    __builtin_amdgcn_global_load_lds(
        (const __attribute__((address_space(1))) unsigned int*)g,
        (__attribute__((address_space(3))) unsigned int*)l, 16, 0, 0);
}
__device__ __forceinline__ unsigned int pack_bf16(float lo, float hi) {
    union { __hip_bfloat162 h; unsigned int u; } w;
    w.h = __float22bfloat162_rn(make_float2(lo, hi));
    return w.u;
}

__global__ __launch_bounds__(512, 4) void attn_kernel(
    const __hip_bfloat16* __restrict__ Qg, const __hip_bfloat16* __restrict__ Gg,
    const __hip_bfloat16* __restrict__ Kg,
    __hip_bfloat16* __restrict__ Opart, float* __restrict__ Lpart, int split)
{
    __shared__ char lds[2][16384];      // [buf][ G 8KB | K 8KB ], XOR-swizzled

    const int blk   = blockIdx.x;
    const int per_b = 16 * split;
    const int b     = blk / per_b;
    const int rem   = blk - b * per_b;
    const int itile = rem / split;
    const int sp    = rem - itile * split;
    const int tid   = threadIdx.x;
    const int wave  = tid >> 6;                   // 0..7
    const int lane  = tid & 63;
    const int l32   = lane & 31;
    const int hi    = lane >> 5;
    const int i0w   = itile * 256 + wave * 32;    // wave's first of 32 rows
    const int jcnt  = NPIX / split;
    const int jlo   = sp * jcnt;
    const int niter = jcnt / KVBLK;

    const short* Qb = (const short*)Qg + (size_t)b * NPIX * CCH;
    const char*  Gb = (const char*)(Gg + (size_t)b * NPIX * CCH);
    const char*  Kb = (const char*)(Kg + (size_t)b * CCH * NPIX);

    // Q B-frags: q[ks] -> Q[i0w+l32][16ks+8hi+t]
    short8 q[4];
    #pragma unroll
    for (int ks = 0; ks < 4; ++ks)
        q[ks] = *(const short8*)(Qb + (size_t)(i0w + l32) * CCH + ks * 16 + hi * 8);

    // hoisted per-lane LDS read bases; per-read addr = base ^ (slot<<4), slot=2ks+hi
    int gbase[2], kbase[2];
    #pragma unroll
    for (int jb = 0; jb < 2; ++jb)
        gbase[jb] = (jb * 32 + l32) * 128 + ((l32 & 7) << 4);
    #pragma unroll
    for (int cb = 0; cb < 2; ++cb)
        kbase[cb] = 8192 + (cb * 32 + l32) * 128 + ((l32 & 7) << 4);

    // hoisted per-lane staging source pointers (512 threads cover 8KB per half)
    const int srow = tid >> 3, scolb = (tid & 7) * 16;
    const char* gsrc = Gb + (size_t)(jlo + srow) * 128 + (scolb ^ ((srow & 7) << 4));
    const char* ksrc = Kb + (size_t)srow * 8192 + (size_t)jlo * 2 + (scolb ^ ((srow & 7) << 4));

    f32x16 zacc;
    #pragma unroll
    for (int r = 0; r < 16; ++r) zacc[r] = 0.f;

    f32x16 o[2];                         // [cb] O^T accumulators (32 rows x 64 ch)
    #pragma unroll
    for (int cb = 0; cb < 2; ++cb)
        #pragma unroll
        for (int r = 0; r < 16; ++r) o[cb][r] = 0.f;
    float ps = 0.f;                      // per-lane denominator partial (i = lane&31)

    auto STAGE = [&](int buf, int tt) {
        gload_lds16(gsrc + tt * (KVBLK * 128), lds[buf] + wave * 1024);
        gload_lds16(ksrc + tt * (KVBLK * 2),  lds[buf] + 8192 + wave * 1024);
    };

    STAGE(0, 0);
    __syncthreads();

    for (int t = 0; t < niter; ++t) {
        const int cur = t & 1;
        STAGE(cur ^ 1, (t + 1 < niter) ? t + 1 : 0);   // uniform (tail re-stages tile 0)
        const char* L = lds[cur];

        // ---- both jb G-frag loads + both QK chains (independent) ----
        short8 ga0[4], ga1[4];
        #pragma unroll
        for (int ks = 0; ks < 4; ++ks) {
            ga0[ks] = *(const short8*)(L + (gbase[0] ^ ((2 * ks + hi) << 4)));
            ga1[ks] = *(const short8*)(L + (gbase[1] ^ ((2 * ks + hi) << 4)));
        }
        __builtin_amdgcn_s_setprio(1);
        f32x16 acc0 = __builtin_amdgcn_mfma_f32_32x32x16_bf16(ga0[0], q[0], zacc, 0, 0, 0);
        f32x16 acc1 = __builtin_amdgcn_mfma_f32_32x32x16_bf16(ga1[0], q[0], zacc, 0, 0, 0);
        acc0 = __builtin_amdgcn_mfma_f32_32x32x16_bf16(ga0[1], q[1], acc0, 0, 0, 0);
        acc1 = __builtin_amdgcn_mfma_f32_32x32x16_bf16(ga1[1], q[1], acc1, 0, 0, 0);
        acc0 = __builtin_amdgcn_mfma_f32_32x32x16_bf16(ga0[2], q[2], acc0, 0, 0, 0);
        acc1 = __builtin_amdgcn_mfma_f32_32x32x16_bf16(ga1[2], q[2], acc1, 0, 0, 0);
        acc0 = __builtin_amdgcn_mfma_f32_32x32x16_bf16(ga0[3], q[3], acc0, 0, 0, 0);
        acc1 = __builtin_amdgcn_mfma_f32_32x32x16_bf16(ga1[3], q[3], acc1, 0, 0, 0);
        __builtin_amdgcn_s_setprio(0);

        #pragma unroll
        for (int jb = 0; jb < 2; ++jb) {
            const f32x16& acc = jb ? acc1 : acc0;
            float p[16];
            #pragma unroll
            for (int r = 0; r < 16; ++r) {
                p[r] = __builtin_amdgcn_exp2f(acc[r]);
                ps += p[r];
            }
            // pack: p[r] holds j_local=(r&3)+8*(r>>2)+4hi; PV B-frag needs
            // lane(hi) to hold j=16kk'+8hi+t. cvt_pk pairs + permlane32_swap (T12).
            short8 pf[2];
            #pragma unroll
            for (int kk = 0; kk < 2; ++kk) {
                unsigned int x0 = pack_bf16(p[8 * kk + 0], p[8 * kk + 1]);
                unsigned int x1 = pack_bf16(p[8 * kk + 2], p[8 * kk + 3]);
                unsigned int y0 = pack_bf16(p[8 * kk + 4], p[8 * kk + 5]);
                unsigned int y1 = pack_bf16(p[8 * kk + 6], p[8 * kk + 7]);
                asm("v_permlane32_swap_b32 %0, %1" : "+v"(x0), "+v"(y0));
                asm("v_permlane32_swap_b32 %0, %1" : "+v"(x1), "+v"(y1));
                union { unsigned int u[4]; short8 v; } w;
                w.u[0] = x0; w.u[1] = x1; w.u[2] = y0; w.u[3] = y1;
                pf[kk] = w.v;
            }

            // PV for this jb's two k-slices (ksg = 2jb+kk)
            __builtin_amdgcn_s_setprio(1);
            #pragma unroll
            for (int kk = 0; kk < 2; ++kk) {
                const int ksg = 2 * jb + kk;
                const short8 ka0 = *(const short8*)(L + (kbase[0] ^ ((2 * ksg + hi) << 4)));
                const short8 ka1 = *(const short8*)(L + (kbase[1] ^ ((2 * ksg + hi) << 4)));
                o[0] = __builtin_amdgcn_mfma_f32_32x32x16_bf16(ka0, pf[kk], o[0], 0, 0, 0);
                o[1] = __builtin_amdgcn_mfma_f32_32x32x16_bf16(ka1, pf[kk], o[1], 0, 0, 0);
            }
            __builtin_amdgcn_s_setprio(0);
        }
        __syncthreads();   // drains staging vmcnt + all waves done reading cur
    }

    // epilogue: O^T is channel-major -> coalesced bf16 stores
    const size_t pb = (size_t)(b * split + sp);
    #pragma unroll
    for (int cb = 0; cb < 2; ++cb)
        #pragma unroll
        for (int r = 0; r < 16; ++r) {
            const int c = cb * 32 + (r & 3) + 8 * (r >> 2) + 4 * hi;
            const int i = i0w + l32;
            Opart[(pb * CCH + c) * NPIX + i] = __float2bfloat16(o[cb][r]);
        }
    // combine hi-halves of the per-lane denominator partial
    ps += __shfl_xor(ps, 32);
    if (lane < 32)
        Lpart[pb * NPIX + i0w + l32] = ps;
}

// ---------------------------------------------------------------------------
// Kernel 2.5: reduce Lpart over splits once -> invL[b][i] = 1/sum_s L.
// Kills combine's 64 MB of redundant Lpart re-reads (64 c-blocks x 8 splits).
// ---------------------------------------------------------------------------
__global__ __launch_bounds__(1024) void lsum_kernel(
    const float* __restrict__ Lpart, float* __restrict__ invL, int split)
{
    const int idx = blockIdx.x * 1024 + threadIdx.x;    // over NB*NPIX
    const int b = idx >> 12, i = idx & 4095;
    float L = 0.f;
    for (int s = 0; s < split; ++s)
        L += Lpart[((size_t)(b * split + s)) * NPIX + i];
    invL[idx] = 1.0f / L;
}

// ---------------------------------------------------------------------------
// Kernel 3: combine split partials: out[b][c][i] = (sum_sp O) * invL + x
// (Opart bf16, channel-major like x/out: no transpose needed.)
// ---------------------------------------------------------------------------
__global__ __launch_bounds__(256) void combine_kernel(
    const __hip_bfloat16* __restrict__ Opart, const float* __restrict__ invL,
    const float* __restrict__ x, float* __restrict__ out, int split)
{
    const int b = blockIdx.x >> 6, c = blockIdx.x & 63;
    #pragma unroll
    for (int chunk = 0; chunk < 2; ++chunk) {
        const int i = chunk * 2048 + threadIdx.x * 8;
        float acc[8] = {0,0,0,0,0,0,0,0};
        for (int s = 0; s < split; ++s) {
            const size_t pb = (size_t)(b * split + s);
            const short8 ov = *(const short8*)((const short*)Opart + (pb * CCH + c) * NPIX + i);
            #pragma unroll
            for (int t = 0; t < 8; ++t) {
                union { unsigned int u; float f; } cv;
                cv.u = ((unsigned int)(unsigned short)ov[t]) << 16;
                acc[t] += cv.f;
            }
        }
        const size_t li = (size_t)b * NPIX + i;
        const f32x4 il0 = *(const f32x4*)&invL[li];
        const f32x4 il1 = *(const f32x4*)&invL[li + 4];
        const size_t idx = ((size_t)b * CCH + c) * NPIX + i;
        const f32x4 xv0 = *(const f32x4*)&x[idx];
        const f32x4 xv1 = *(const f32x4*)&x[idx + 4];
        f32x4 r0, r1;
        #pragma unroll
        for (int t = 0; t < 4; ++t) {
            r0[t] = acc[t] * il0[t] + xv0[t];
            r1[t] = acc[t + 4] * il1[t] + xv1[t];
        }
        *(f32x4*)&out[idx]     = r0;
        *(f32x4*)&out[idx + 4] = r1;
    }
}

extern "C" void kernel_launch(void* const* d_in, const int* in_sizes, int n_in,
                              void* d_out, int out_size, void* d_ws, size_t ws_size,
                              hipStream_t stream) {
    const float* x  = (const float*)d_in[0];
    const float* W1 = (const float*)d_in[1];
    const float* b1 = (const float*)d_in[2];
    const float* W2 = (const float*)d_in[3];
    const float* b2 = (const float*)d_in[4];
    const float* W3 = (const float*)d_in[5];
    const float* b3 = (const float*)d_in[6];
    float* out = (float*)d_out;

    char* ws = (char*)d_ws;
    const size_t planeB = (size_t)NB * NPIX * CCH * sizeof(__hip_bfloat16); // 4 MB
    __hip_bfloat16* Q = (__hip_bfloat16*)(ws);
    __hip_bfloat16* G = (__hip_bfloat16*)(ws + planeB);
    __hip_bfloat16* K = (__hip_bfloat16*)(ws + 2 * planeB);

    const size_t base   = 3 * planeB;                               // 12 MB
    const size_t oPlane = planeB;                                   // 4 MB per split (bf16)
    const size_t lPlane = (size_t)NB * NPIX * sizeof(float);        // 128 KB per split

    // prefer split=8 (1024 blocks); fall back if ws is tight
    int split = 8;
    while (split > 1 && base + (size_t)split * (oPlane + lPlane) > ws_size)
        split >>= 1;

    __hip_bfloat16* Opart = (__hip_bfloat16*)(ws + base);
    float* Lpart = (float*)(ws + base + (size_t)split * oPlane);
    float* invL  = (float*)(ws);   // reuse Q region (Q consumed by attn before lsum)

    proj_kernel<<<dim3(NB * 64 * 3), dim3(256), 0, stream>>>(x, W1, b1, W2, b2, W3, b3, Q, G, K);
    attn_kernel<<<dim3(NB * 16 * split), dim3(512), 0, stream>>>(Q, G, K, Opart, Lpart, split);
    lsum_kernel<<<dim3(NB * NPIX / 1024), dim3(1024), 0, stream>>>(Lpart, invL, split);
    combine_kernel<<<dim3(NB * CCH), dim3(256), 0, stream>>>(Opart, invL, x, out, split);
}

// Round 16
// 84.958 us; speedup vs baseline: 1.0070x; 1.0070x over previous
//
#include <hip/hip_runtime.h>
#include <hip/hip_bf16.h>

#define NPIX 4096   // 64*64 pixels per batch
#define CCH  64     // channels
#define NB   8      // batch
#define KVBLK 64    // j-tile per pipeline stage (32KB LDS dbuf)

typedef __attribute__((ext_vector_type(8)))  short short8;   // 8 bf16 MFMA A/B frag (32x32x16)
typedef __attribute__((ext_vector_type(4)))  float f32x4;
typedef __attribute__((ext_vector_type(16))) float f32x16;   // 32x32 MFMA C/D frag

#define LOG2E   1.44269504f

// ---------------------------------------------------------------------------
// Kernel 1: fused 1x1-conv projections, m-split across blocks (R14-proven).
//   m=0: Q[b][i][oc] = log2e * (W1 x + b1)   (bf16 pixel-major)
//   m=1: G[b][j][oc] =         (W2 x + b2)   (bf16 pixel-major)
//   m=2: K[b][oc][j] =         (W3 x + b3)   (bf16 channel-major)
// ---------------------------------------------------------------------------
__global__ __launch_bounds__(256) void proj_kernel(
    const float* __restrict__ x,
    const float* __restrict__ W1, const float* __restrict__ b1,
    const float* __restrict__ W2, const float* __restrict__ b2,
    const float* __restrict__ W3, const float* __restrict__ b3,
    __hip_bfloat16* __restrict__ Q, __hip_bfloat16* __restrict__ G,
    __hip_bfloat16* __restrict__ K)
{
    const int m    = blockIdx.x % 3;
    const int tile = blockIdx.x / 3;
    const int b    = tile >> 6;
    const int i0   = (tile & 63) << 6;

    const float* W  = (m == 0) ? W1 : (m == 1) ? W2 : W3;
    const float* bv = (m == 0) ? b1 : (m == 1) ? b2 : b3;

    __shared__ float xs[64][65];      // xs[c][p]
    __shared__ float Wt[64][68];      // Wt[c][oc], rows 16B-aligned

    for (int e = threadIdx.x; e < 4096; e += 256) {
        const int c = e >> 6, p = e & 63;
        xs[c][p] = x[(size_t)b * CCH * NPIX + (size_t)c * NPIX + i0 + p];
        Wt[e & 63][e >> 6] = W[e];
    }
    __syncthreads();

    const int p = threadIdx.x & 63;
    const int g = threadIdx.x >> 6;

    float acc[16];
    #pragma unroll
    for (int oo = 0; oo < 16; ++oo) acc[oo] = bv[g * 16 + oo];

    for (int c = 0; c < 64; ++c) {
        const float xv = xs[c][p];
        const f32x4* w = (const f32x4*)&Wt[c][g * 16];
        #pragma unroll
        for (int qq = 0; qq < 4; ++qq) {
            const f32x4 a = w[qq];
            #pragma unroll
            for (int j = 0; j < 4; ++j)
                acc[qq * 4 + j] += a[j] * xv;
        }
    }

    const int i = i0 + p;
    if (m == 0) {
        #pragma unroll
        for (int oo = 0; oo < 16; ++oo)
            Q[(size_t)b * NPIX * CCH + (size_t)i * CCH + g * 16 + oo] =
                __float2bfloat16(acc[oo] * LOG2E);
    } else if (m == 1) {
        #pragma unroll
        for (int oo = 0; oo < 16; ++oo)
            G[(size_t)b * NPIX * CCH + (size_t)i * CCH + g * 16 + oo] =
                __float2bfloat16(acc[oo]);
    } else {
        #pragma unroll
        for (int oo = 0; oo < 16; ++oo)
            K[(size_t)b * CCH * NPIX + (size_t)(g * 16 + oo) * NPIX + i] =
                __float2bfloat16(acc[oo]);
    }
}

// ---------------------------------------------------------------------------
// Kernel 2: LDS-staged flash attention, 32x32x16 MFMA, swapped QK^T, KVBLK=64.
// 8 waves x 32 rows (512 threads), R14 per-jb structure (R15's two-jb
// pipeline regressed and is reverted).
// R16 delta: denominator via ones-MFMA lacc instead of the serial
// ps += exp chain (1024 dependent fadds/wave, ~4cyc latency each, strict-FP
// unbreakable). Moves the row-sum to the 26%-busy MFMA pipe; +16 VGPR.
// lacc path proven correct in R4/R7-R10.
// Compiler-visible exp->pack chain (builtin exp2f + __float22bfloat162_rn);
// only permlane stays asm (R3-R15-proven safe boundary).
// 32x32x16 bf16 layouts (m74/m101-verified C/D; A/B contiguous-8k):
//   A: row=lane&31, k=8*(lane>>5)+t     B: col=lane&31, k=8*(lane>>5)+t
//   C/D: col=lane&31, row=(r&3)+8*(r>>2)+4*(lane>>5)
// LDS per buf: G[64 rows][128B] swz ^(row&7)<<4, K[64 c-rows][128B] same.
// ---------------------------------------------------------------------------
__device__ __forceinline__ void gload_lds16(const void* g, void* l) {
    __builtin_amdgcn_global_load_lds(
        (const __attribute__((address_space(1))) unsigned int*)g,
        (__attribute__((address_space(3))) unsigned int*)l, 16, 0, 0);
}
__device__ __forceinline__ unsigned int pack_bf16(float lo, float hi) {
    union { __hip_bfloat162 h; unsigned int u; } w;
    w.h = __float22bfloat162_rn(make_float2(lo, hi));
    return w.u;
}

__global__ __launch_bounds__(512, 4) void attn_kernel(
    const __hip_bfloat16* __restrict__ Qg, const __hip_bfloat16* __restrict__ Gg,
    const __hip_bfloat16* __restrict__ Kg,
    __hip_bfloat16* __restrict__ Opart, float* __restrict__ Lpart, int split)
{
    __shared__ char lds[2][16384];      // [buf][ G 8KB | K 8KB ], XOR-swizzled

    const int blk   = blockIdx.x;
    const int per_b = 16 * split;
    const int b     = blk / per_b;
    const int rem   = blk - b * per_b;
    const int itile = rem / split;
    const int sp    = rem - itile * split;
    const int tid   = threadIdx.x;
    const int wave  = tid >> 6;                   // 0..7
    const int lane  = tid & 63;
    const int l32   = lane & 31;
    const int hi    = lane >> 5;
    const int i0w   = itile * 256 + wave * 32;    // wave's first of 32 rows
    const int jcnt  = NPIX / split;
    const int jlo   = sp * jcnt;
    const int niter = jcnt / KVBLK;

    const short* Qb = (const short*)Qg + (size_t)b * NPIX * CCH;
    const char*  Gb = (const char*)(Gg + (size_t)b * NPIX * CCH);
    const char*  Kb = (const char*)(Kg + (size_t)b * CCH * NPIX);

    // Q B-frags: q[ks] -> Q[i0w+l32][16ks+8hi+t]
    short8 q[4];
    #pragma unroll
    for (int ks = 0; ks < 4; ++ks)
        q[ks] = *(const short8*)(Qb + (size_t)(i0w + l32) * CCH + ks * 16 + hi * 8);

    // hoisted per-lane LDS read bases; per-read addr = base ^ (slot<<4), slot=2ks+hi
    int gbase[2], kbase[2];
    #pragma unroll
    for (int jb = 0; jb < 2; ++jb)
        gbase[jb] = (jb * 32 + l32) * 128 + ((l32 & 7) << 4);
    #pragma unroll
    for (int cb = 0; cb < 2; ++cb)
        kbase[cb] = 8192 + (cb * 32 + l32) * 128 + ((l32 & 7) << 4);

    // hoisted per-lane staging source pointers (512 threads cover 8KB per half)
    const int srow = tid >> 3, scolb = (tid & 7) * 16;
    const char* gsrc = Gb + (size_t)(jlo + srow) * 128 + (scolb ^ ((srow & 7) << 4));
    const char* ksrc = Kb + (size_t)srow * 8192 + (size_t)jlo * 2 + (scolb ^ ((srow & 7) << 4));

    f32x16 zacc;
    #pragma unroll
    for (int r = 0; r < 16; ++r) zacc[r] = 0.f;
    short8 ones;
    #pragma unroll
    for (int t = 0; t < 8; ++t) ones[t] = (short)0x3F80;   // bf16 1.0

    f32x16 o[2];                         // [cb] O^T accumulators (32 rows x 64 ch)
    #pragma unroll
    for (int cb = 0; cb < 2; ++cb)
        #pragma unroll
        for (int r = 0; r < 16; ++r) o[cb][r] = 0.f;
    f32x16 lacc;                         // denominator accumulator (ones-MFMA)
    #pragma unroll
    for (int r = 0; r < 16; ++r) lacc[r] = 0.f;

    auto STAGE = [&](int buf, int tt) {
        gload_lds16(gsrc + tt * (KVBLK * 128), lds[buf] + wave * 1024);
        gload_lds16(ksrc + tt * (KVBLK * 2),  lds[buf] + 8192 + wave * 1024);
    };

    STAGE(0, 0);
    __syncthreads();

    for (int t = 0; t < niter; ++t) {
        const int cur = t & 1;
        STAGE(cur ^ 1, (t + 1 < niter) ? t + 1 : 0);   // uniform (tail re-stages tile 0)
        const char* L = lds[cur];

        #pragma unroll
        for (int jb = 0; jb < 2; ++jb) {
            short8 ga[4];
            #pragma unroll
            for (int ks = 0; ks < 4; ++ks)
                ga[ks] = *(const short8*)(L + (gbase[jb] ^ ((2 * ks + hi) << 4)));

            __builtin_amdgcn_s_setprio(1);
            f32x16 acc = __builtin_amdgcn_mfma_f32_32x32x16_bf16(ga[0], q[0], zacc, 0, 0, 0);
            acc = __builtin_amdgcn_mfma_f32_32x32x16_bf16(ga[1], q[1], acc, 0, 0, 0);
            acc = __builtin_amdgcn_mfma_f32_32x32x16_bf16(ga[2], q[2], acc, 0, 0, 0);
            acc = __builtin_amdgcn_mfma_f32_32x32x16_bf16(ga[3], q[3], acc, 0, 0, 0);
            __builtin_amdgcn_s_setprio(0);

            float p[16];
            #pragma unroll
            for (int r = 0; r < 16; ++r)
                p[r] = __builtin_amdgcn_exp2f(acc[r]);
            // pack: p[r] holds j_local=(r&3)+8*(r>>2)+4hi; PV B-frag needs
            // lane(hi) to hold j=16kk'+8hi+t. cvt_pk pairs + permlane32_swap (T12).
            short8 pf[2];
            #pragma unroll
            for (int kk = 0; kk < 2; ++kk) {
                unsigned int x0 = pack_bf16(p[8 * kk + 0], p[8 * kk + 1]);
                unsigned int x1 = pack_bf16(p[8 * kk + 2], p[8 * kk + 3]);
                unsigned int y0 = pack_bf16(p[8 * kk + 4], p[8 * kk + 5]);
                unsigned int y1 = pack_bf16(p[8 * kk + 6], p[8 * kk + 7]);
                asm("v_permlane32_swap_b32 %0, %1" : "+v"(x0), "+v"(y0));
                asm("v_permlane32_swap_b32 %0, %1" : "+v"(x1), "+v"(y1));
                union { unsigned int u[4]; short8 v; } w;
                w.u[0] = x0; w.u[1] = x1; w.u[2] = y0; w.u[3] = y1;
                pf[kk] = w.v;
            }

            // PV for this jb's two k-slices (ksg = 2jb+kk); lacc row-sum on MFMA pipe
            __builtin_amdgcn_s_setprio(1);
            #pragma unroll
            for (int kk = 0; kk < 2; ++kk) {
                const int ksg = 2 * jb + kk;
                const short8 ka0 = *(const short8*)(L + (kbase[0] ^ ((2 * ksg + hi) << 4)));
                const short8 ka1 = *(const short8*)(L + (kbase[1] ^ ((2 * ksg + hi) << 4)));
                o[0] = __builtin_amdgcn_mfma_f32_32x32x16_bf16(ka0, pf[kk], o[0], 0, 0, 0);
                o[1] = __builtin_amdgcn_mfma_f32_32x32x16_bf16(ka1, pf[kk], o[1], 0, 0, 0);
                lacc = __builtin_amdgcn_mfma_f32_32x32x16_bf16(ones, pf[kk], lacc, 0, 0, 0);
            }
            __builtin_amdgcn_s_setprio(0);
        }
        __syncthreads();   // drains staging vmcnt + all waves done reading cur
    }

    // epilogue: O^T is channel-major -> coalesced bf16 stores
    const size_t pb = (size_t)(b * split + sp);
    #pragma unroll
    for (int cb = 0; cb < 2; ++cb)
        #pragma unroll
        for (int r = 0; r < 16; ++r) {
            const int c = cb * 32 + (r & 3) + 8 * (r >> 2) + 4 * hi;
            const int i = i0w + l32;
            Opart[(pb * CCH + c) * NPIX + i] = __float2bfloat16(o[cb][r]);
        }
    // lacc rows identical (ones A): reg 0 holds L[i] for i=lane&31
    if (lane < 32)
        Lpart[pb * NPIX + i0w + l32] = lacc[0];
}

// ---------------------------------------------------------------------------
// Kernel 3: combine split partials: out[b][c][i] = sum_sp O / sum_sp L + x
// (Opart bf16, channel-major like x/out; Lpart L2-resident so re-reads are
// cheap — R15's lsum/invL pre-pass regressed and is reverted.)
// ---------------------------------------------------------------------------
__global__ __launch_bounds__(256) void combine_kernel(
    const __hip_bfloat16* __restrict__ Opart, const float* __restrict__ Lpart,
    const float* __restrict__ x, float* __restrict__ out, int split)
{
    const int b = blockIdx.x >> 6, c = blockIdx.x & 63;
    #pragma unroll
    for (int chunk = 0; chunk < 2; ++chunk) {
        const int i = chunk * 2048 + threadIdx.x * 8;
        float acc[8] = {0,0,0,0,0,0,0,0};
        float Ls[8]  = {0,0,0,0,0,0,0,0};
        for (int s = 0; s < split; ++s) {
            const size_t pb = (size_t)(b * split + s);
            const short8 ov = *(const short8*)((const short*)Opart + (pb * CCH + c) * NPIX + i);
            const f32x4 l0 = *(const f32x4*)&Lpart[pb * NPIX + i];
            const f32x4 l1 = *(const f32x4*)&Lpart[pb * NPIX + i + 4];
            #pragma unroll
            for (int t = 0; t < 8; ++t) {
                union { unsigned int u; float f; } cv;
                cv.u = ((unsigned int)(unsigned short)ov[t]) << 16;
                acc[t] += cv.f;
                Ls[t]  += (t < 4) ? l0[t] : l1[t - 4];
            }
        }
        const size_t idx = ((size_t)b * CCH + c) * NPIX + i;
        const f32x4 xv0 = *(const f32x4*)&x[idx];
        const f32x4 xv1 = *(const f32x4*)&x[idx + 4];
        f32x4 r0, r1;
        #pragma unroll
        for (int t = 0; t < 4; ++t) {
            r0[t] = acc[t] / Ls[t] + xv0[t];
            r1[t] = acc[t + 4] / Ls[t + 4] + xv1[t];
        }
        *(f32x4*)&out[idx]     = r0;
        *(f32x4*)&out[idx + 4] = r1;
    }
}

extern "C" void kernel_launch(void* const* d_in, const int* in_sizes, int n_in,
                              void* d_out, int out_size, void* d_ws, size_t ws_size,
                              hipStream_t stream) {
    const float* x  = (const float*)d_in[0];
    const float* W1 = (const float*)d_in[1];
    const float* b1 = (const float*)d_in[2];
    const float* W2 = (const float*)d_in[3];
    const float* b2 = (const float*)d_in[4];
    const float* W3 = (const float*)d_in[5];
    const float* b3 = (const float*)d_in[6];
    float* out = (float*)d_out;

    char* ws = (char*)d_ws;
    const size_t planeB = (size_t)NB * NPIX * CCH * sizeof(__hip_bfloat16); // 4 MB
    __hip_bfloat16* Q = (__hip_bfloat16*)(ws);
    __hip_bfloat16* G = (__hip_bfloat16*)(ws + planeB);
    __hip_bfloat16* K = (__hip_bfloat16*)(ws + 2 * planeB);

    const size_t base   = 3 * planeB;                               // 12 MB
    const size_t oPlane = planeB;                                   // 4 MB per split (bf16)
    const size_t lPlane = (size_t)NB * NPIX * sizeof(float);        // 128 KB per split

    // prefer split=8 (1024 blocks); fall back if ws is tight
    int split = 8;
    while (split > 1 && base + (size_t)split * (oPlane + lPlane) > ws_size)
        split >>= 1;

    __hip_bfloat16* Opart = (__hip_bfloat16*)(ws + base);
    float* Lpart = (float*)(ws + base + (size_t)split * oPlane);

    proj_kernel<<<dim3(NB * 64 * 3), dim3(256), 0, stream>>>(x, W1, b1, W2, b2, W3, b3, Q, G, K);
    attn_kernel<<<dim3(NB * 16 * split), dim3(512), 0, stream>>>(Q, G, K, Opart, Lpart, split);
    combine_kernel<<<dim3(NB * CCH), dim3(256), 0, stream>>>(Opart, Lpart, x, out, split);
}

// Round 17
// 83.322 us; speedup vs baseline: 1.0268x; 1.0196x over previous
//
#include <hip/hip_runtime.h>
#include <hip/hip_bf16.h>

#define NPIX 4096   // 64*64 pixels per batch
#define CCH  64     // channels
#define NB   8      // batch
#define KVBLK 64    // j-tile per pipeline stage (16KB/buf, 3 bufs = 48KB LDS)

typedef __attribute__((ext_vector_type(8)))  short short8;   // 8 bf16 MFMA A/B frag (32x32x16)
typedef __attribute__((ext_vector_type(4)))  float f32x4;
typedef __attribute__((ext_vector_type(16))) float f32x16;   // 32x32 MFMA C/D frag

#define LOG2E   1.44269504f

// ---------------------------------------------------------------------------
// Kernel 1: fused 1x1-conv projections, m-split across blocks (R14-proven).
// ---------------------------------------------------------------------------
__global__ __launch_bounds__(256) void proj_kernel(
    const float* __restrict__ x,
    const float* __restrict__ W1, const float* __restrict__ b1,
    const float* __restrict__ W2, const float* __restrict__ b2,
    const float* __restrict__ W3, const float* __restrict__ b3,
    __hip_bfloat16* __restrict__ Q, __hip_bfloat16* __restrict__ G,
    __hip_bfloat16* __restrict__ K)
{
    const int m    = blockIdx.x % 3;
    const int tile = blockIdx.x / 3;
    const int b    = tile >> 6;
    const int i0   = (tile & 63) << 6;

    const float* W  = (m == 0) ? W1 : (m == 1) ? W2 : W3;
    const float* bv = (m == 0) ? b1 : (m == 1) ? b2 : b3;

    __shared__ float xs[64][65];      // xs[c][p]
    __shared__ float Wt[64][68];      // Wt[c][oc]

    for (int e = threadIdx.x; e < 4096; e += 256) {
        const int c = e >> 6, p = e & 63;
        xs[c][p] = x[(size_t)b * CCH * NPIX + (size_t)c * NPIX + i0 + p];
        Wt[e & 63][e >> 6] = W[e];
    }
    __syncthreads();

    const int p = threadIdx.x & 63;
    const int g = threadIdx.x >> 6;

    float acc[16];
    #pragma unroll
    for (int oo = 0; oo < 16; ++oo) acc[oo] = bv[g * 16 + oo];

    for (int c = 0; c < 64; ++c) {
        const float xv = xs[c][p];
        const f32x4* w = (const f32x4*)&Wt[c][g * 16];
        #pragma unroll
        for (int qq = 0; qq < 4; ++qq) {
            const f32x4 a = w[qq];
            #pragma unroll
            for (int j = 0; j < 4; ++j)
                acc[qq * 4 + j] += a[j] * xv;
        }
    }

    const int i = i0 + p;
    if (m == 0) {
        #pragma unroll
        for (int oo = 0; oo < 16; ++oo)
            Q[(size_t)b * NPIX * CCH + (size_t)i * CCH + g * 16 + oo] =
                __float2bfloat16(acc[oo] * LOG2E);
    } else if (m == 1) {
        #pragma unroll
        for (int oo = 0; oo < 16; ++oo)
            G[(size_t)b * NPIX * CCH + (size_t)i * CCH + g * 16 + oo] =
                __float2bfloat16(acc[oo]);
    } else {
        #pragma unroll
        for (int oo = 0; oo < 16; ++oo)
            K[(size_t)b * CCH * NPIX + (size_t)(g * 16 + oo) * NPIX + i] =
                __float2bfloat16(acc[oo]);
    }
}

// ---------------------------------------------------------------------------
// Kernel 2: LDS-staged flash attention, 32x32x16 MFMA, swapped QK^T, KVBLK=64.
// 8 waves x 32 rows (512 threads). R17 delta: TRIPLE-buffered staging with
// counted vmcnt(2) + raw s_barrier (replaces __syncthreads' vmcnt(0) drain).
// Stage for t+2 issues at iter t; at iter end we drain only tile-(t+1)'s
// loads (vmcnt(2) leaves the 2 newest in flight across the barrier) -> a
// full iteration of latency hiding for each stage.
// Safety: buf[(t+2)%3]'s last readers (iter t-1) pass the t-1 barrier before
// the stage issues; sched_barrier(0) fences both sides (rule 18).
// ps VALU row-sum (R14 form; R16's lacc regressed). Compiler-visible exp->
// pack chain; only permlane stays asm.
// 32x32x16 bf16 layouts (m74/m101-verified C/D; A/B contiguous-8k):
//   A: row=lane&31, k=8*(lane>>5)+t     B: col=lane&31, k=8*(lane>>5)+t
//   C/D: col=lane&31, row=(r&3)+8*(r>>2)+4*(lane>>5)
// LDS per buf: G[64 rows][128B] swz ^(row&7)<<4, K[64 c-rows][128B] same.
// ---------------------------------------------------------------------------
__device__ __forceinline__ void gload_lds16(const void* g, void* l) {
    __builtin_amdgcn_global_load_lds(
        (const __attribute__((address_space(1))) unsigned int*)g,
        (__attribute__((address_space(3))) unsigned int*)l, 16, 0, 0);
}
__device__ __forceinline__ unsigned int pack_bf16(float lo, float hi) {
    union { __hip_bfloat162 h; unsigned int u; } w;
    w.h = __float22bfloat162_rn(make_float2(lo, hi));
    return w.u;
}
__device__ __forceinline__ void pipe_barrier() {
    asm volatile("s_waitcnt vmcnt(2)" ::: "memory");
    __builtin_amdgcn_sched_barrier(0);
    __builtin_amdgcn_s_barrier();
    __builtin_amdgcn_sched_barrier(0);
}

__global__ __launch_bounds__(512, 4) void attn_kernel(
    const __hip_bfloat16* __restrict__ Qg, const __hip_bfloat16* __restrict__ Gg,
    const __hip_bfloat16* __restrict__ Kg,
    __hip_bfloat16* __restrict__ Opart, float* __restrict__ Lpart, int split)
{
    __shared__ char lds[3][16384];      // [buf][ G 8KB | K 8KB ], XOR-swizzled

    const int blk   = blockIdx.x;
    const int per_b = 16 * split;
    const int b     = blk / per_b;
    const int rem   = blk - b * per_b;
    const int itile = rem / split;
    const int sp    = rem - itile * split;
    const int tid   = threadIdx.x;
    const int wave  = tid >> 6;                   // 0..7
    const int lane  = tid & 63;
    const int l32   = lane & 31;
    const int hi    = lane >> 5;
    const int i0w   = itile * 256 + wave * 32;    // wave's first of 32 rows
    const int jcnt  = NPIX / split;
    const int jlo   = sp * jcnt;
    const int niter = jcnt / KVBLK;               // >= 8

    const short* Qb = (const short*)Qg + (size_t)b * NPIX * CCH;
    const char*  Gb = (const char*)(Gg + (size_t)b * NPIX * CCH);
    const char*  Kb = (const char*)(Kg + (size_t)b * CCH * NPIX);

    // Q B-frags: q[ks] -> Q[i0w+l32][16ks+8hi+t]
    short8 q[4];
    #pragma unroll
    for (int ks = 0; ks < 4; ++ks)
        q[ks] = *(const short8*)(Qb + (size_t)(i0w + l32) * CCH + ks * 16 + hi * 8);

    // hoisted per-lane LDS read bases; per-read addr = base ^ (slot<<4), slot=2ks+hi
    int gbase[2], kbase[2];
    #pragma unroll
    for (int jb = 0; jb < 2; ++jb)
        gbase[jb] = (jb * 32 + l32) * 128 + ((l32 & 7) << 4);
    #pragma unroll
    for (int cb = 0; cb < 2; ++cb)
        kbase[cb] = 8192 + (cb * 32 + l32) * 128 + ((l32 & 7) << 4);

    // hoisted per-lane staging source pointers (512 threads cover 8KB per half)
    const int srow = tid >> 3, scolb = (tid & 7) * 16;
    const char* gsrc = Gb + (size_t)(jlo + srow) * 128 + (scolb ^ ((srow & 7) << 4));
    const char* ksrc = Kb + (size_t)srow * 8192 + (size_t)jlo * 2 + (scolb ^ ((srow & 7) << 4));

    f32x16 zacc;
    #pragma unroll
    for (int r = 0; r < 16; ++r) zacc[r] = 0.f;

    f32x16 o[2];                         // [cb] O^T accumulators (32 rows x 64 ch)
    #pragma unroll
    for (int cb = 0; cb < 2; ++cb)
        #pragma unroll
        for (int r = 0; r < 16; ++r) o[cb][r] = 0.f;
    float ps = 0.f;                      // per-lane denominator partial (i = lane&31)

    auto STAGE = [&](int buf, int tt) {
        gload_lds16(gsrc + tt * (KVBLK * 128), lds[buf] + wave * 1024);
        gload_lds16(ksrc + tt * (KVBLK * 2),  lds[buf] + 8192 + wave * 1024);
    };

    // prologue: 2-deep prefetch
    STAGE(0, 0);
    STAGE(1, 1);
    pipe_barrier();                      // drains tile-0's loads, keeps tile-1's

    int cur = 0;
    for (int t = 0; t < niter; ++t) {
        const int nxt2 = (cur == 0) ? 2 : (cur == 1) ? 0 : 1;   // (t+2)%3
        STAGE(nxt2, (t + 2 < niter) ? t + 2 : 0);   // tail stages never-read buf
        const char* L = lds[cur];

        #pragma unroll
        for (int jb = 0; jb < 2; ++jb) {
            short8 ga[4];
            #pragma unroll
            for (int ks = 0; ks < 4; ++ks)
                ga[ks] = *(const short8*)(L + (gbase[jb] ^ ((2 * ks + hi) << 4)));

            __builtin_amdgcn_s_setprio(1);
            f32x16 acc = __builtin_amdgcn_mfma_f32_32x32x16_bf16(ga[0], q[0], zacc, 0, 0, 0);
            acc = __builtin_amdgcn_mfma_f32_32x32x16_bf16(ga[1], q[1], acc, 0, 0, 0);
            acc = __builtin_amdgcn_mfma_f32_32x32x16_bf16(ga[2], q[2], acc, 0, 0, 0);
            acc = __builtin_amdgcn_mfma_f32_32x32x16_bf16(ga[3], q[3], acc, 0, 0, 0);
            __builtin_amdgcn_s_setprio(0);

            float p[16];
            #pragma unroll
            for (int r = 0; r < 16; ++r) {
                p[r] = __builtin_amdgcn_exp2f(acc[r]);
                ps += p[r];
            }
            // pack: p[r] holds j_local=(r&3)+8*(r>>2)+4hi; PV B-frag needs
            // lane(hi) to hold j=16kk'+8hi+t. cvt_pk pairs + permlane32_swap (T12).
            short8 pf[2];
            #pragma unroll
            for (int kk = 0; kk < 2; ++kk) {
                unsigned int x0 = pack_bf16(p[8 * kk + 0], p[8 * kk + 1]);
                unsigned int x1 = pack_bf16(p[8 * kk + 2], p[8 * kk + 3]);
                unsigned int y0 = pack_bf16(p[8 * kk + 4], p[8 * kk + 5]);
                unsigned int y1 = pack_bf16(p[8 * kk + 6], p[8 * kk + 7]);
                asm("v_permlane32_swap_b32 %0, %1" : "+v"(x0), "+v"(y0));
                asm("v_permlane32_swap_b32 %0, %1" : "+v"(x1), "+v"(y1));
                union { unsigned int u[4]; short8 v; } w;
                w.u[0] = x0; w.u[1] = x1; w.u[2] = y0; w.u[3] = y1;
                pf[kk] = w.v;
            }

            // PV for this jb's two k-slices (ksg = 2jb+kk)
            __builtin_amdgcn_s_setprio(1);
            #pragma unroll
            for (int kk = 0; kk < 2; ++kk) {
                const int ksg = 2 * jb + kk;
                const short8 ka0 = *(const short8*)(L + (kbase[0] ^ ((2 * ksg + hi) << 4)));
                const short8 ka1 = *(const short8*)(L + (kbase[1] ^ ((2 * ksg + hi) << 4)));
                o[0] = __builtin_amdgcn_mfma_f32_32x32x16_bf16(ka0, pf[kk], o[0], 0, 0, 0);
                o[1] = __builtin_amdgcn_mfma_f32_32x32x16_bf16(ka1, pf[kk], o[1], 0, 0, 0);
            }
            __builtin_amdgcn_s_setprio(0);
        }
        pipe_barrier();   // drains tile-(t+1)'s loads; tile-(t+2)'s stay in flight
        cur = (cur == 2) ? 0 : cur + 1;
    }

    // epilogue: O^T is channel-major -> coalesced bf16 stores
    const size_t pb = (size_t)(b * split + sp);
    #pragma unroll
    for (int cb = 0; cb < 2; ++cb)
        #pragma unroll
        for (int r = 0; r < 16; ++r) {
            const int c = cb * 32 + (r & 3) + 8 * (r >> 2) + 4 * hi;
            const int i = i0w + l32;
            Opart[(pb * CCH + c) * NPIX + i] = __float2bfloat16(o[cb][r]);
        }
    // combine hi-halves of the per-lane denominator partial
    ps += __shfl_xor(ps, 32);
    if (lane < 32)
        Lpart[pb * NPIX + i0w + l32] = ps;
}

// ---------------------------------------------------------------------------
// Kernel 3: combine, stripe form (R17). Block = (b, 64-pixel stripe), all 64
// channels. Lpart reduced ONCE into LDS invL (1MB total read vs 64MB logical
// in the per-channel-block form). out = (sum_sp O) * invL + x.
// ---------------------------------------------------------------------------
__global__ __launch_bounds__(256) void combine_kernel(
    const __hip_bfloat16* __restrict__ Opart, const float* __restrict__ Lpart,
    const float* __restrict__ x, float* __restrict__ out, int split)
{
    const int b  = blockIdx.x >> 6;
    const int i0 = (blockIdx.x & 63) << 6;

    __shared__ float invL[64];
    if (threadIdx.x < 64) {
        const int i = i0 + threadIdx.x;
        float L = 0.f;
        for (int s = 0; s < split; ++s)
            L += Lpart[((size_t)(b * split + s)) * NPIX + i];
        invL[threadIdx.x] = 1.0f / L;
    }
    __syncthreads();

    const int c    = threadIdx.x >> 2;        // 0..63
    const int ioff = (threadIdx.x & 3) * 16;  // 16 pixels per thread

    float acc[16];
    #pragma unroll
    for (int k = 0; k < 16; ++k) acc[k] = 0.f;

    for (int s = 0; s < split; ++s) {
        const size_t base = (((size_t)(b * split + s)) * CCH + c) * NPIX + i0 + ioff;
        const short8 v0 = *(const short8*)((const short*)Opart + base);
        const short8 v1 = *(const short8*)((const short*)Opart + base + 8);
        #pragma unroll
        for (int k = 0; k < 8; ++k) {
            union { unsigned int u; float f; } cv0, cv1;
            cv0.u = ((unsigned int)(unsigned short)v0[k]) << 16;
            cv1.u = ((unsigned int)(unsigned short)v1[k]) << 16;
            acc[k]     += cv0.f;
            acc[k + 8] += cv1.f;
        }
    }

    const size_t idx = ((size_t)b * CCH + c) * NPIX + i0 + ioff;
    #pragma unroll
    for (int kq = 0; kq < 4; ++kq) {
        const f32x4 xv = *(const f32x4*)&x[idx + 4 * kq];
        f32x4 r;
        #pragma unroll
        for (int t = 0; t < 4; ++t)
            r[t] = acc[kq * 4 + t] * invL[ioff + kq * 4 + t] + xv[t];
        *(f32x4*)&out[idx + 4 * kq] = r;
    }
}

extern "C" void kernel_launch(void* const* d_in, const int* in_sizes, int n_in,
                              void* d_out, int out_size, void* d_ws, size_t ws_size,
                              hipStream_t stream) {
    const float* x  = (const float*)d_in[0];
    const float* W1 = (const float*)d_in[1];
    const float* b1 = (const float*)d_in[2];
    const float* W2 = (const float*)d_in[3];
    const float* b2 = (const float*)d_in[4];
    const float* W3 = (const float*)d_in[5];
    const float* b3 = (const float*)d_in[6];
    float* out = (float*)d_out;

    char* ws = (char*)d_ws;
    const size_t planeB = (size_t)NB * NPIX * CCH * sizeof(__hip_bfloat16); // 4 MB
    __hip_bfloat16* Q = (__hip_bfloat16*)(ws);
    __hip_bfloat16* G = (__hip_bfloat16*)(ws + planeB);
    __hip_bfloat16* K = (__hip_bfloat16*)(ws + 2 * planeB);

    const size_t base   = 3 * planeB;                               // 12 MB
    const size_t oPlane = planeB;                                   // 4 MB per split (bf16)
    const size_t lPlane = (size_t)NB * NPIX * sizeof(float);        // 128 KB per split

    // prefer split=8 (1024 blocks); fall back if ws is tight
    int split = 8;
    while (split > 1 && base + (size_t)split * (oPlane + lPlane) > ws_size)
        split >>= 1;

    __hip_bfloat16* Opart = (__hip_bfloat16*)(ws + base);
    float* Lpart = (float*)(ws + base + (size_t)split * oPlane);

    proj_kernel<<<dim3(NB * 64 * 3), dim3(256), 0, stream>>>(x, W1, b1, W2, b2, W3, b3, Q, G, K);
    attn_kernel<<<dim3(NB * 16 * split), dim3(512), 0, stream>>>(Q, G, K, Opart, Lpart, split);
    combine_kernel<<<dim3(NB * 64), dim3(256), 0, stream>>>(Opart, Lpart, x, out, split);
}